// Round 27
// baseline (27.931 us; speedup 1.0000x reference)
//
#include <hip/hip_runtime.h>
#include <math.h>

typedef float v2f __attribute__((ext_vector_type(2)));

// Problem constants (fixed by setup_inputs)
constexpr int B_  = 8;
constexpr int C_  = 64;
constexpr int H_  = 112;
constexpr int W_  = 112;
constexpr int KH  = 5;
constexpr int KW  = 5;

constexpr int SEG    = 14;            // output rows per wave-task
constexpr int NSEG   = 8;             // 8 segments cover H=112
constexpr int STEPS  = SEG + KH - 1;  // 18 input rows walked per wave
constexpr int NPAIR  = 56;            // active lanes (2 cols each) cover W=112
constexpr int TPB    = 256;           // 4 independent wave-tasks per block
constexpr int NTASK  = B_ * C_ * NSEG;  // 4096 wave-tasks
constexpr int DEPTH  = 4;             // prefetch distance (steps ahead)
constexpr int RING   = 5;             // ring size > DEPTH: write (i+4)%5 never
                                      // collides with read i%5 (R25 bug: ring==DEPTH
                                      // made write slot == read slot -> absmax 6.2)

// uniform float -> SGPR: readfirstlane moves BITS; bit-cast both ways.
__device__ __forceinline__ float uniform_f32(float v) {
    return __int_as_float(__builtin_amdgcn_readfirstlane(__float_as_int(v)));
}

// ---------------------------------------------------------------------------
// Pure-register streaming soft-morphology (func_type==1) — NO LDS, NO barriers,
// depth-4 prefetch (ring-5), 4 waves/SIMD. (R22 ran depth-2 at 2 waves/SIMD:
// latency-exposed on both axes; this fixes both.)
// Wave = (plane, 14-row segment); lane l handles cols 2l,2l+1 (56/64 active).
// Ring of 5 pending output rows in registers; input row r feeds outputs
// r-2..r+2; a completed row is stored immediately (coalesced v2f).
// Math: E=e^{aK x}, F'=aK x E (pad => ax=0 => E=1,F'=0 in ONE select);
// u=e^{a w}, v=w u in SGPRs; (Z,N') += (u,u)*(E,F') pk_fma; nm2 += v*E;
// out = s*(N'/a + nm2)*rcp(Z) + s*bias.
// Fully unrolled (18 steps): ring slots and ramp/drain guards compile-time.
// ---------------------------------------------------------------------------
__global__ __launch_bounds__(TPB)
void morpho_stream4(const float* __restrict__ x,
                    const float* __restrict__ weight,
                    const float* __restrict__ bias,
                    const float* __restrict__ sign,
                    const int*   __restrict__ alpha_p,
                    float* __restrict__ out)
{
    const int wv    = threadIdx.x >> 6;        // wave in block
    const int lane  = threadIdx.x & 63;
    const int task  = blockIdx.x * 4 + wv;     // 0..4095
    const int plane = task >> 3;               // 0..511 (b*C + c)
    const int seg   = task & 7;                // 0..7
    const int c     = plane & (C_ - 1);

    const bool active = (lane < NPAIR);
    const int  g   = active ? lane : (NPAIR - 1);   // col-pair 0..55
    const int  r0  = seg * SEG - 2;                 // input row at step 0
    const int  cL  = 2 * g - 2;                     // window base col

    const float sg    = sign[0];
    const float seff  = (fabsf(sg) >= 1e-7f) ? sg : 1.0f;
    const float a     = (float)alpha_p[0];
    const float aK    = a * seff;                   // ax = aK * raw_x
    const float inv_a = 1.0f / a;

    const float* xp = x + (size_t)plane * (H_ * W_);
    float*       op = out + (size_t)plane * (H_ * W_);

    // clamped, 8B-aligned bases for the 3 v2f of the 6-col window
    const int b0 = (cL < 0) ? 0 : cL;                       // g==0 edge
    const int b1 = cL + 2;                                  // = 2g, valid
    const int b2 = (cL + 4 > W_ - 2) ? (W_ - 2) : (cL + 4); // g==55 edge
    bool cok[6];
#pragma unroll
    for (int j = 0; j < 6; ++j) cok[j] = (cL + j >= 0) && (cL + j < W_);

    // ---- prefetch steps 0..3 into ring slots 0..3 ----
    v2f xv[RING][3];
#pragma unroll
    for (int m = 0; m < DEPTH; ++m) {
        int gr = min(max(r0 + m, 0), H_ - 1);
        const float* row = xp + gr * W_;
        xv[m][0] = *reinterpret_cast<const v2f*>(row + b0);
        xv[m][1] = *reinterpret_cast<const v2f*>(row + b1);
        xv[m][2] = *reinterpret_cast<const v2f*>(row + b2);
    }

    // ---- per-wave-uniform weight transforms -> SGPRs (overlap load latency) ----
    const float* wp = weight + c * (KH * KW);
    float su[KH * KW], sv[KH * KW];
#pragma unroll
    for (int k = 0; k < KH * KW; ++k) {
        float wvv = wp[k];
        float u   = __expf(a * wvv);
        su[k] = uniform_f32(u);
        sv[k] = uniform_f32(wvv * u);
    }
    const float sb = seff * bias[c];

    // ring: slot s5 holds output row ro with (ro - seg*SEG) % 5 == s5
    v2f   acc[5][2];
    float nm2[5][2];
#pragma unroll
    for (int s5 = 0; s5 < 5; ++s5)
#pragma unroll
        for (int c2 = 0; c2 < 2; ++c2) { acc[s5][c2] = (v2f){0.0f, 0.0f}; nm2[s5][c2] = 0.0f; }

#pragma unroll
    for (int i = 0; i < STEPS; ++i) {
        // ---- issue loads for step i+DEPTH into slot (i+DEPTH)%RING ----
        if (i + DEPTH < STEPS) {
            int gr = min(max(r0 + i + DEPTH, 0), H_ - 1);
            const float* row = xp + gr * W_;
            const int ws = (i + DEPTH) % RING;     // != i%RING (RING > DEPTH)
            xv[ws][0] = *reinterpret_cast<const v2f*>(row + b0);
            xv[ws][1] = *reinterpret_cast<const v2f*>(row + b1);
            xv[ws][2] = *reinterpret_cast<const v2f*>(row + b2);
        }

        // ---- build E/F' window from slot i%RING (pad => ax=0 => E=1,F'=0) ----
        const int  r   = r0 + i;
        const bool rok = (r >= 0) && (r < H_);
        const int  rs  = i % RING;
        v2f ew[6];
#pragma unroll
        for (int j = 0; j < 6; ++j) {
            float xj = xv[rs][j >> 1][j & 1];
            float ax = (rok && cok[j]) ? aK * xj : 0.0f;
            float e  = __expf(ax);
            ew[j] = (v2f){e, ax * e};
        }

        // ---- accumulate into the 5 pending rows (guards compile-time) ----
#pragma unroll
        for (int k = 0; k < KH; ++k) {
            const int d = i - k;               // ro - seg*SEG
            if (d < 0 || d >= SEG) continue;
            const int s5 = d % 5;
#pragma unroll
            for (int j = 0; j < KW; ++j) {
                const float u  = su[k * 5 + j];
                const v2f   u2 = (v2f){u, u};
                const float v  = sv[k * 5 + j];
#pragma unroll
                for (int c2 = 0; c2 < 2; ++c2) {
                    acc[s5][c2] = __builtin_elementwise_fma(u2, ew[c2 + j], acc[s5][c2]);
                    nm2[s5][c2] = fmaf(v, ew[c2 + j].x, nm2[s5][c2]);
                }
            }
        }

        // ---- row ro = r-2 completes at step i>=4: store + reset slot ----
        if (i >= 4) {
            const int d  = i - 4;
            const int s5 = d % 5;
            const int ro = seg * SEG + d;
            float o0, o1;
            {
                float Z   = acc[s5][0].x;
                float num = fmaf(acc[s5][0].y, inv_a, nm2[s5][0]);
                o0 = fmaf(seff * num, __builtin_amdgcn_rcpf(Z), sb);
            }
            {
                float Z   = acc[s5][1].x;
                float num = fmaf(acc[s5][1].y, inv_a, nm2[s5][1]);
                o1 = fmaf(seff * num, __builtin_amdgcn_rcpf(Z), sb);
            }
            if (active)
                *reinterpret_cast<v2f*>(op + (size_t)ro * W_ + 2 * g) = (v2f){o0, o1};
            acc[s5][0] = (v2f){0.0f, 0.0f};
            acc[s5][1] = (v2f){0.0f, 0.0f};
            nm2[s5][0] = 0.0f;
            nm2[s5][1] = 0.0f;
        }
    }
}

extern "C" void kernel_launch(void* const* d_in, const int* in_sizes, int n_in,
                              void* d_out, int out_size, void* d_ws, size_t ws_size,
                              hipStream_t stream) {
    // setup_inputs order: x, weight, bias, sign, padding, stride, func_type, alpha
    const float* x      = (const float*)d_in[0];
    const float* weight = (const float*)d_in[1];
    const float* bias   = (const float*)d_in[2];
    const float* sign   = (const float*)d_in[3];
    const int*   alpha  = (const int*)d_in[7];
    float* out = (float*)d_out;

    dim3 grid(NTASK / 4);   // 1024 blocks x 4 independent waves = 4 waves/SIMD
    morpho_stream4<<<grid, TPB, 0, stream>>>(x, weight, bias, sign, alpha, out);
}